// Round 1
// baseline (431.289 us; speedup 1.0000x reference)
//
#include <hip/hip_runtime.h>

#define WINDOW 500
#define NSHIFT 125   // MAX_STRIDE=125, STRIDE=1

// One wave (64 lanes) per window of 500 elements.
__global__ __launch_bounds__(64) void window_ccc_kernel(
    const float* __restrict__ pred,
    const float* __restrict__ gt,
    float* __restrict__ accum,
    int num_wins)
{
    const int w = blockIdx.x;
    if (w >= num_wins) return;
    const int lane = threadIdx.x;  // 0..63
    const float* p = pred + (size_t)w * WINDOW;
    const float* g = gt   + (size_t)w * WINDOW;

    // Per-lane partial totals over the window
    float sp = 0.f, spp = 0.f, spg = 0.f, sg = 0.f, sgg = 0.f;
    // Element values for iterations 0 and 1 (elements 0..63 and 64..127),
    // needed for the prefix scans at shift offsets 0..124.
    float p0 = 0.f, pp0 = 0.f, pg0 = 0.f;
    float p1 = 0.f, pp1 = 0.f, pg1 = 0.f;

    #pragma unroll
    for (int k = 0; k < 8; ++k) {
        int idx = k * 64 + lane;
        float pv = 0.f, gv = 0.f;
        if (idx < WINDOW) { pv = p[idx]; gv = g[idx]; }
        float ppv = pv * pv;
        float pgv = pv * gv;
        sp += pv; spp += ppv; spg += pgv;
        sg += gv; sgg += gv * gv;
        if (k == 0) { p0 = pv; pp0 = ppv; pg0 = pgv; }
        if (k == 1) { p1 = pv; pp1 = ppv; pg1 = pgv; }
    }

    // Wave-wide totals (butterfly): all lanes end with full sums.
    #pragma unroll
    for (int off = 32; off >= 1; off >>= 1) {
        sp  += __shfl_xor(sp,  off);
        spp += __shfl_xor(spp, off);
        spg += __shfl_xor(spg, off);
        sg  += __shfl_xor(sg,  off);
        sgg += __shfl_xor(sgg, off);
    }

    // Inclusive scans across lanes for iter-0 and iter-1 triples.
    float s_p0 = p0, s_pp0 = pp0, s_pg0 = pg0;
    float s_p1 = p1, s_pp1 = pp1, s_pg1 = pg1;
    #pragma unroll
    for (int off = 1; off <= 32; off <<= 1) {
        float t;
        t = __shfl_up(s_p0,  off); if (lane >= off) s_p0  += t;
        t = __shfl_up(s_pp0, off); if (lane >= off) s_pp0 += t;
        t = __shfl_up(s_pg0, off); if (lane >= off) s_pg0 += t;
        t = __shfl_up(s_p1,  off); if (lane >= off) s_p1  += t;
        t = __shfl_up(s_pp1, off); if (lane >= off) s_pp1 += t;
        t = __shfl_up(s_pg1, off); if (lane >= off) s_pg1 += t;
    }

    // Exclusive prefix at n = lane (elements < n):
    float e_p0 = s_p0 - p0, e_pp0 = s_pp0 - pp0, e_pg0 = s_pg0 - pg0;
    // Totals of iteration 0 (elements 0..63) = inclusive scan at lane 63:
    float t_p0  = __shfl(s_p0,  63);
    float t_pp0 = __shfl(s_pp0, 63);
    float t_pg0 = __shfl(s_pg0, 63);
    // Exclusive prefix at n = 64 + lane:
    float e_p1  = t_p0  + s_p1  - p1;
    float e_pp1 = t_pp0 + s_pp1 - pp1;
    float e_pg1 = t_pg0 + s_pg1 - pg1;

    const float Wf   = (float)WINDOW;
    const float Wm1  = (float)(WINDOW - 1);
    const float m_g   = sg / Wf;
    const float var_g = (sgg - Wf * m_g * m_g) / Wm1;

    float cmin;
    {   // shift n = lane (0..63)
        float Sp  = sp  - e_p0;
        float Spp = spp - e_pp0;
        float Spg = spg - e_pg0;
        float m_p   = Sp / Wf;
        float var_p = (Spp - Wf * m_p * m_p) / Wm1;
        float cov   = Spg / Wf - m_p * m_g;
        float d     = m_g - m_p;
        cmin = 2.0f * cov / (var_g + var_p + d * d);
    }
    if (lane <= 60) {  // shift n = 64 + lane (64..124)
        float Sp  = sp  - e_p1;
        float Spp = spp - e_pp1;
        float Spg = spg - e_pg1;
        float m_p   = Sp / Wf;
        float var_p = (Spp - Wf * m_p * m_p) / Wm1;
        float cov   = Spg / Wf - m_p * m_g;
        float d     = m_g - m_p;
        float ccc   = 2.0f * cov / (var_g + var_p + d * d);
        cmin = fminf(cmin, ccc);
    }

    // Wave min-reduce
    #pragma unroll
    for (int off = 32; off >= 1; off >>= 1)
        cmin = fminf(cmin, __shfl_xor(cmin, off));

    if (lane == 0) atomicAdd(accum, cmin);
}

__global__ void window_ccc_finalize(const float* __restrict__ accum,
                                    float* __restrict__ out, int num_wins)
{
    out[0] = 1.0f - accum[0] / (float)num_wins;
}

extern "C" void kernel_launch(void* const* d_in, const int* in_sizes, int n_in,
                              void* d_out, int out_size, void* d_ws, size_t ws_size,
                              hipStream_t stream) {
    const float* pred = (const float*)d_in[0];
    const float* gt   = (const float*)d_in[1];
    float* out   = (float*)d_out;
    float* accum = (float*)d_ws;

    const int L = in_sizes[0];
    const int num_wins = L / WINDOW;

    hipMemsetAsync(accum, 0, sizeof(float), stream);
    window_ccc_kernel<<<num_wins, 64, 0, stream>>>(pred, gt, accum, num_wins);
    window_ccc_finalize<<<1, 1, 0, stream>>>(accum, out, num_wins);
}

// Round 2
// 37.063 us; speedup vs baseline: 11.6365x; 11.6365x over previous
//
#include <hip/hip_runtime.h>
#include <float.h>

#define WINDOW  500
#define NQUADS  125     // 500 floats = 125 float4 per window (window stride is 16B-aligned)
#define NSHIFT  125
#define WPB     4       // windows (one wave each) per 256-thread block

// One wave per window. Round-0: lane l holds float4 quad l (elements 4l..4l+3).
// Round-1: lanes 0..60 hold quad 64+l. Shift n=4q+r is evaluated by lane q (<32)
// using an exclusive cross-lane scan of quad sums + in-quad local prefixes.
template <bool TWO_STAGE>
__global__ __launch_bounds__(256) void window_ccc_kernel(
    const float4* __restrict__ pred4,
    const float4* __restrict__ gt4,
    float* __restrict__ block_out,   // TWO_STAGE: per-block partial sums; else: single accum
    int num_wins)
{
    __shared__ float s_cmin[WPB];
    const int wave = threadIdx.x >> 6;
    const int lane = threadIdx.x & 63;
    int w = blockIdx.x * WPB + wave;
    const bool valid = (w < num_wins);
    if (!valid) w = num_wins - 1;   // safe address; contribution zeroed below

    const float4* p4 = pred4 + (size_t)w * NQUADS;
    const float4* g4 = gt4   + (size_t)w * NQUADS;

    float4 pa = p4[lane];
    float4 ga = g4[lane];
    float4 pb = make_float4(0.f, 0.f, 0.f, 0.f);
    float4 gb = make_float4(0.f, 0.f, 0.f, 0.f);
    if (lane < NQUADS - 64) { pb = p4[64 + lane]; gb = g4[64 + lane]; }

    // Round-0 quad sums (feed the prefix scan)
    const float qp  = pa.x + pa.y + pa.z + pa.w;
    const float qpp = pa.x*pa.x + pa.y*pa.y + pa.z*pa.z + pa.w*pa.w;
    const float qpg = pa.x*ga.x + pa.y*ga.y + pa.z*ga.z + pa.w*ga.w;

    // Per-lane totals over both rounds
    float sp  = qp  + pb.x + pb.y + pb.z + pb.w;
    float spp = qpp + pb.x*pb.x + pb.y*pb.y + pb.z*pb.z + pb.w*pb.w;
    float spg = qpg + pb.x*gb.x + pb.y*gb.y + pb.z*gb.z + pb.w*gb.w;
    float sg  = ga.x + ga.y + ga.z + ga.w + gb.x + gb.y + gb.z + gb.w;
    float sgg = ga.x*ga.x + ga.y*ga.y + ga.z*ga.z + ga.w*ga.w
              + gb.x*gb.x + gb.y*gb.y + gb.z*gb.z + gb.w*gb.w;

    // 64-lane butterfly: all lanes get window totals
    #pragma unroll
    for (int off = 32; off >= 1; off >>= 1) {
        sp  += __shfl_xor(sp,  off);
        spp += __shfl_xor(spp, off);
        spg += __shfl_xor(spg, off);
        sg  += __shfl_xor(sg,  off);
        sgg += __shfl_xor(sgg, off);
    }

    // Inclusive scan of round-0 quad sums; 5 steps suffice for lanes 0..31
    float c_p = qp, c_pp = qpp, c_pg = qpg;
    #pragma unroll
    for (int off = 1; off <= 16; off <<= 1) {
        float t;
        t = __shfl_up(c_p,  off); if (lane >= off) c_p  += t;
        t = __shfl_up(c_pp, off); if (lane >= off) c_pp += t;
        t = __shfl_up(c_pg, off); if (lane >= off) c_pg += t;
    }

    const float Wf = (float)WINDOW, Wm1 = (float)(WINDOW - 1);
    const float m_g   = sg / Wf;
    const float var_g = (sgg - Wf * m_g * m_g) / Wm1;

    float cmin = FLT_MAX;
    if (lane < 32) {
        const float e_p  = c_p  - qp;    // exclusive prefix of quads < lane
        const float e_pp = c_pp - qpp;
        const float e_pg = c_pg - qpg;
        // in-quad local prefixes (r = #elements of this quad included)
        float lp0 = 0.f,             lpp0 = 0.f,                 lpg0 = 0.f;
        float lp1 = pa.x,            lpp1 = pa.x*pa.x,           lpg1 = pa.x*ga.x;
        float lp2 = lp1 + pa.y,      lpp2 = lpp1 + pa.y*pa.y,    lpg2 = lpg1 + pa.y*ga.y;
        float lp3 = lp2 + pa.z,      lpp3 = lpp2 + pa.z*pa.z,    lpg3 = lpg2 + pa.z*ga.z;
        const int base = lane * 4;
        #pragma unroll
        for (int r = 0; r < 4; ++r) {
            float lp  = (r == 0) ? lp0  : (r == 1) ? lp1  : (r == 2) ? lp2  : lp3;
            float lpp = (r == 0) ? lpp0 : (r == 1) ? lpp1 : (r == 2) ? lpp2 : lpp3;
            float lpg = (r == 0) ? lpg0 : (r == 1) ? lpg1 : (r == 2) ? lpg2 : lpg3;
            if (base + r < NSHIFT) {
                float Sp  = sp  - (e_p  + lp);
                float Spp = spp - (e_pp + lpp);
                float Spg = spg - (e_pg + lpg);
                float m_p   = Sp / Wf;
                float var_p = (Spp - Wf * m_p * m_p) / Wm1;
                float cov   = Spg / Wf - m_p * m_g;
                float d     = m_g - m_p;
                float ccc   = 2.0f * cov / (var_g + var_p + d * d);
                cmin = fminf(cmin, ccc);
            }
        }
    }

    // Wave min-reduce
    #pragma unroll
    for (int off = 32; off >= 1; off >>= 1)
        cmin = fminf(cmin, __shfl_xor(cmin, off));

    if (lane == 0) s_cmin[wave] = valid ? cmin : 0.f;
    __syncthreads();
    if (threadIdx.x == 0) {
        float s = s_cmin[0] + s_cmin[1] + s_cmin[2] + s_cmin[3];
        if (TWO_STAGE) block_out[blockIdx.x] = s;
        else           atomicAdd(block_out, s);
    }
}

__global__ __launch_bounds__(256) void window_ccc_finalize(
    const float* __restrict__ block_sums, int nblocks,
    float* __restrict__ out, int num_wins)
{
    float s = 0.f;
    for (int i = threadIdx.x; i < nblocks; i += 256) s += block_sums[i];
    #pragma unroll
    for (int off = 32; off >= 1; off >>= 1) s += __shfl_xor(s, off);
    __shared__ float ws[4];
    const int wave = threadIdx.x >> 6, lane = threadIdx.x & 63;
    if (lane == 0) ws[wave] = s;
    __syncthreads();
    if (threadIdx.x == 0)
        out[0] = 1.0f - (ws[0] + ws[1] + ws[2] + ws[3]) / (float)num_wins;
}

extern "C" void kernel_launch(void* const* d_in, const int* in_sizes, int n_in,
                              void* d_out, int out_size, void* d_ws, size_t ws_size,
                              hipStream_t stream) {
    const float4* pred4 = (const float4*)d_in[0];
    const float4* gt4   = (const float4*)d_in[1];
    float* out = (float*)d_out;
    float* ws  = (float*)d_ws;

    const int L = in_sizes[0];
    const int num_wins = L / WINDOW;
    const int nblocks  = (num_wins + WPB - 1) / WPB;

    if (ws_size >= (size_t)nblocks * sizeof(float)) {
        window_ccc_kernel<true><<<nblocks, 256, 0, stream>>>(pred4, gt4, ws, num_wins);
        window_ccc_finalize<<<1, 256, 0, stream>>>(ws, nblocks, out, num_wins);
    } else {
        hipMemsetAsync(ws, 0, sizeof(float), stream);
        window_ccc_kernel<false><<<nblocks, 256, 0, stream>>>(pred4, gt4, ws, num_wins);
        window_ccc_finalize<<<1, 256, 0, stream>>>(ws, 1, out, num_wins);
    }
}

// Round 3
// 34.227 us; speedup vs baseline: 12.6010x; 1.0829x over previous
//
#include <hip/hip_runtime.h>
#include <float.h>

#define WINDOW  500
#define NQUADS  125     // 500 floats = 125 float4 per window
#define NSHIFT  125
#define WPB     4       // windows (one wave each) per 256-thread block

// ---- DPP cross-lane primitives (VALU, no LDS) -----------------------------
// Classic GCN 64-lane inclusive scan: row_shr 1/2/4/8 then row_bcast15/31.
template <int CTRL, int RM>
__device__ __forceinline__ float dpp_add_step(float x) {
    int t = __builtin_amdgcn_update_dpp(0, __float_as_int(x), CTRL, RM, 0xf, false);
    return x + __int_as_float(t);   // masked/invalid lanes add old=0 (identity)
}
__device__ __forceinline__ float scan64_add(float x) {
    x = dpp_add_step<0x111, 0xf>(x);   // row_shr:1
    x = dpp_add_step<0x112, 0xf>(x);   // row_shr:2
    x = dpp_add_step<0x114, 0xf>(x);   // row_shr:4
    x = dpp_add_step<0x118, 0xf>(x);   // row_shr:8
    x = dpp_add_step<0x142, 0xa>(x);   // row_bcast:15 -> rows 1,3
    x = dpp_add_step<0x143, 0xc>(x);   // row_bcast:31 -> rows 2,3
    return x;                          // lane63 holds the wave total
}
template <int CTRL, int RM>
__device__ __forceinline__ float dpp_min_step(float x) {
    int t = __builtin_amdgcn_update_dpp(0x7f800000 /*+inf*/, __float_as_int(x),
                                        CTRL, RM, 0xf, false);
    return fminf(x, __int_as_float(t));  // masked/invalid -> +inf (identity)
}
__device__ __forceinline__ float wave_min64(float x) {
    x = dpp_min_step<0x111, 0xf>(x);
    x = dpp_min_step<0x112, 0xf>(x);
    x = dpp_min_step<0x114, 0xf>(x);
    x = dpp_min_step<0x118, 0xf>(x);
    x = dpp_min_step<0x142, 0xa>(x);
    x = dpp_min_step<0x143, 0xc>(x);
    return __int_as_float(__builtin_amdgcn_readlane(__float_as_int(x), 63));
}
__device__ __forceinline__ float rl63(float x) {
    return __int_as_float(__builtin_amdgcn_readlane(__float_as_int(x), 63));
}
// rcp + one Newton step (~1e-7 rel err; output threshold is 2e-2)
__device__ __forceinline__ float frcp(float x) {
    float r = __builtin_amdgcn_rcpf(x);
    return r * (2.0f - x * r);
}

__device__ __forceinline__ float ccc_eval(float Sp, float Spp, float Spg,
                                          float m_g, float var_g) {
    const float invW   = 1.0f / (float)WINDOW;
    const float invWm1 = 1.0f / (float)(WINDOW - 1);
    float m_p   = Sp * invW;
    float var_p = (Spp - (float)WINDOW * m_p * m_p) * invWm1;
    float cov   = Spg * invW - m_p * m_g;
    float d     = m_g - m_p;
    return 2.0f * cov * frcp(var_g + var_p + d * d);
}

// One wave per window: lane l holds quad l (elems 4l..4l+3) and quad 64+l.
// Shift n=4q+r is evaluated by lane q (<32) from the scan of round-0 quads.
template <bool TWO_STAGE>
__global__ __launch_bounds__(256) void window_ccc_kernel(
    const float4* __restrict__ pred4,
    const float4* __restrict__ gt4,
    float* __restrict__ block_out,
    int num_wins)
{
    __shared__ float s_cmin[WPB];
    const int wave = threadIdx.x >> 6;
    const int lane = threadIdx.x & 63;
    int w = blockIdx.x * WPB + wave;
    const bool valid = (w < num_wins);
    if (!valid) w = num_wins - 1;

    const float4* p4 = pred4 + (size_t)w * NQUADS;
    const float4* g4 = gt4   + (size_t)w * NQUADS;

    float4 pa = p4[lane];
    float4 ga = g4[lane];
    float4 pb = make_float4(0.f, 0.f, 0.f, 0.f);
    float4 gb = make_float4(0.f, 0.f, 0.f, 0.f);
    if (lane < NQUADS - 64) { pb = p4[64 + lane]; gb = g4[64 + lane]; }

    // Round-0 quad sums (feed the prefix scan at shifts 0..124)
    const float qp  = pa.x + pa.y + pa.z + pa.w;
    const float qpp = pa.x*pa.x + pa.y*pa.y + pa.z*pa.z + pa.w*pa.w;
    const float qpg = pa.x*ga.x + pa.y*ga.y + pa.z*ga.z + pa.w*ga.w;
    // Round-1 quad sums (totals only)
    const float r1p  = pb.x + pb.y + pb.z + pb.w;
    const float r1pp = pb.x*pb.x + pb.y*pb.y + pb.z*pb.z + pb.w*pb.w;
    const float r1pg = pb.x*gb.x + pb.y*gb.y + pb.z*gb.z + pb.w*gb.w;
    // g stats need totals only: combine both rounds per lane
    const float lg  = ga.x + ga.y + ga.z + ga.w + gb.x + gb.y + gb.z + gb.w;
    const float lgg = ga.x*ga.x + ga.y*ga.y + ga.z*ga.z + ga.w*ga.w
                    + gb.x*gb.x + gb.y*gb.y + gb.z*gb.z + gb.w*gb.w;

    // 8 DPP scans (inclusive); wave totals read from lane 63 as uniforms
    float c_p  = scan64_add(qp);
    float c_pp = scan64_add(qpp);
    float c_pg = scan64_add(qpg);
    float t1p  = scan64_add(r1p);
    float t1pp = scan64_add(r1pp);
    float t1pg = scan64_add(r1pg);
    float tg   = scan64_add(lg);
    float tgg  = scan64_add(lgg);

    const float sp  = rl63(c_p)  + rl63(t1p);
    const float spp = rl63(c_pp) + rl63(t1pp);
    const float spg = rl63(c_pg) + rl63(t1pg);
    const float sg  = rl63(tg);
    const float sgg = rl63(tgg);

    const float invW   = 1.0f / (float)WINDOW;
    const float invWm1 = 1.0f / (float)(WINDOW - 1);
    const float m_g   = sg * invW;
    const float var_g = (sgg - (float)WINDOW * m_g * m_g) * invWm1;

    float cmin = FLT_MAX;
    if (lane < 32) {
        // suffix sums at n = 4*lane (exclusive prefix of quads < lane)
        float Sp  = sp  - (c_p  - qp);
        float Spp = spp - (c_pp - qpp);
        float Spg = spg - (c_pg - qpg);
        const int base = lane * 4;
        cmin = ccc_eval(Sp, Spp, Spg, m_g, var_g);                    // r=0
        Sp -= pa.x; Spp -= pa.x*pa.x; Spg -= pa.x*ga.x;               // r=1
        if (base + 1 < NSHIFT) cmin = fminf(cmin, ccc_eval(Sp, Spp, Spg, m_g, var_g));
        Sp -= pa.y; Spp -= pa.y*pa.y; Spg -= pa.y*ga.y;               // r=2
        if (base + 2 < NSHIFT) cmin = fminf(cmin, ccc_eval(Sp, Spp, Spg, m_g, var_g));
        Sp -= pa.z; Spp -= pa.z*pa.z; Spg -= pa.z*ga.z;               // r=3
        if (base + 3 < NSHIFT) cmin = fminf(cmin, ccc_eval(Sp, Spp, Spg, m_g, var_g));
    }

    const float cm = wave_min64(cmin);   // uniform

    if (lane == 0) s_cmin[wave] = valid ? cm : 0.f;
    __syncthreads();
    if (threadIdx.x == 0) {
        float s = s_cmin[0] + s_cmin[1] + s_cmin[2] + s_cmin[3];
        if (TWO_STAGE) block_out[blockIdx.x] = s;
        else           atomicAdd(block_out, s);
    }
}

__global__ __launch_bounds__(256) void window_ccc_finalize(
    const float* __restrict__ block_sums, int nblocks,
    float* __restrict__ out, int num_wins)
{
    float s = 0.f;
    for (int i = threadIdx.x; i < nblocks; i += 256) s += block_sums[i];
    #pragma unroll
    for (int off = 32; off >= 1; off >>= 1) s += __shfl_xor(s, off);
    __shared__ float ws[4];
    const int wave = threadIdx.x >> 6, lane = threadIdx.x & 63;
    if (lane == 0) ws[wave] = s;
    __syncthreads();
    if (threadIdx.x == 0)
        out[0] = 1.0f - (ws[0] + ws[1] + ws[2] + ws[3]) / (float)num_wins;
}

extern "C" void kernel_launch(void* const* d_in, const int* in_sizes, int n_in,
                              void* d_out, int out_size, void* d_ws, size_t ws_size,
                              hipStream_t stream) {
    const float4* pred4 = (const float4*)d_in[0];
    const float4* gt4   = (const float4*)d_in[1];
    float* out = (float*)d_out;
    float* ws  = (float*)d_ws;

    const int L = in_sizes[0];
    const int num_wins = L / WINDOW;
    const int nblocks  = (num_wins + WPB - 1) / WPB;

    if (ws_size >= (size_t)nblocks * sizeof(float)) {
        window_ccc_kernel<true><<<nblocks, 256, 0, stream>>>(pred4, gt4, ws, num_wins);
        window_ccc_finalize<<<1, 256, 0, stream>>>(ws, nblocks, out, num_wins);
    } else {
        hipMemsetAsync(ws, 0, sizeof(float), stream);
        window_ccc_kernel<false><<<nblocks, 256, 0, stream>>>(pred4, gt4, ws, num_wins);
        window_ccc_finalize<<<1, 256, 0, stream>>>(ws, 1, out, num_wins);
    }
}

// Round 4
// 29.926 us; speedup vs baseline: 14.4120x; 1.1437x over previous
//
#include <hip/hip_runtime.h>
#include <float.h>

#define WINDOW  500
#define NQUADS  125     // 500 floats = 125 float4 per window
#define NSHIFT  125
#define WPB     4       // waves per 256-thread block
#define NWPW    4       // windows per wave (software-pipelined)

// ---- DPP cross-lane primitives (VALU, no LDS) -----------------------------
template <int CTRL, int RM>
__device__ __forceinline__ float dpp_add_step(float x) {
    int t = __builtin_amdgcn_update_dpp(0, __float_as_int(x), CTRL, RM, 0xf, false);
    return x + __int_as_float(t);
}
__device__ __forceinline__ float scan64_add(float x) {
    x = dpp_add_step<0x111, 0xf>(x);   // row_shr:1
    x = dpp_add_step<0x112, 0xf>(x);   // row_shr:2
    x = dpp_add_step<0x114, 0xf>(x);   // row_shr:4
    x = dpp_add_step<0x118, 0xf>(x);   // row_shr:8
    x = dpp_add_step<0x142, 0xa>(x);   // row_bcast:15 -> rows 1,3
    x = dpp_add_step<0x143, 0xc>(x);   // row_bcast:31 -> rows 2,3
    return x;                          // lane63 = wave total
}
template <int CTRL, int RM>
__device__ __forceinline__ float dpp_min_step(float x) {
    int t = __builtin_amdgcn_update_dpp(0x7f800000, __float_as_int(x), CTRL, RM, 0xf, false);
    return fminf(x, __int_as_float(t));
}
__device__ __forceinline__ float wave_min64(float x) {
    x = dpp_min_step<0x111, 0xf>(x);
    x = dpp_min_step<0x112, 0xf>(x);
    x = dpp_min_step<0x114, 0xf>(x);
    x = dpp_min_step<0x118, 0xf>(x);
    x = dpp_min_step<0x142, 0xa>(x);
    x = dpp_min_step<0x143, 0xc>(x);
    return __int_as_float(__builtin_amdgcn_readlane(__float_as_int(x), 63));
}
__device__ __forceinline__ float rl63(float x) {
    return __int_as_float(__builtin_amdgcn_readlane(__float_as_int(x), 63));
}
__device__ __forceinline__ float frcp(float x) {
    float r = __builtin_amdgcn_rcpf(x);
    return r * (2.0f - x * r);   // 1 Newton step, ~1e-7 rel err
}

__device__ __forceinline__ float ccc_eval(float Sp, float Spp, float Spg,
                                          float m_g, float var_g) {
    const float invW   = 1.0f / (float)WINDOW;
    const float invWm1 = 1.0f / (float)(WINDOW - 1);
    float m_p   = Sp * invW;
    float var_p = (Spp - (float)WINDOW * m_p * m_p) * invWm1;
    float cov   = Spg * invW - m_p * m_g;
    float d     = m_g - m_p;
    return 2.0f * cov * frcp(var_g + var_p + d * d);
}

struct Win { float4 pa, ga, pb, gb; };

__device__ __forceinline__ void load_win(const float4* __restrict__ pred4,
                                         const float4* __restrict__ gt4,
                                         int w, int lane, Win& d)
{
    const float4* p4 = pred4 + (size_t)w * NQUADS;
    const float4* g4 = gt4   + (size_t)w * NQUADS;
    d.pa = p4[lane];
    d.ga = g4[lane];
    d.pb = make_float4(0.f, 0.f, 0.f, 0.f);
    d.gb = make_float4(0.f, 0.f, 0.f, 0.f);
    if (lane < NQUADS - 64) { d.pb = p4[64 + lane]; d.gb = g4[64 + lane]; }
}

// Full per-window pipeline; returns wave-uniform min-ccc over the 125 shifts.
__device__ __forceinline__ float compute_win(const Win& d, int lane)
{
    const float4 pa = d.pa, ga = d.ga, pb = d.pb, gb = d.gb;

    const float qp  = pa.x + pa.y + pa.z + pa.w;
    const float qpp = pa.x*pa.x + pa.y*pa.y + pa.z*pa.z + pa.w*pa.w;
    const float qpg = pa.x*ga.x + pa.y*ga.y + pa.z*ga.z + pa.w*ga.w;
    const float r1p  = pb.x + pb.y + pb.z + pb.w;
    const float r1pp = pb.x*pb.x + pb.y*pb.y + pb.z*pb.z + pb.w*pb.w;
    const float r1pg = pb.x*gb.x + pb.y*gb.y + pb.z*gb.z + pb.w*gb.w;
    const float lg  = ga.x + ga.y + ga.z + ga.w + gb.x + gb.y + gb.z + gb.w;
    const float lgg = ga.x*ga.x + ga.y*ga.y + ga.z*ga.z + ga.w*ga.w
                    + gb.x*gb.x + gb.y*gb.y + gb.z*gb.z + gb.w*gb.w;

    float c_p  = scan64_add(qp);
    float c_pp = scan64_add(qpp);
    float c_pg = scan64_add(qpg);
    const float sp  = rl63(c_p)  + rl63(scan64_add(r1p));
    const float spp = rl63(c_pp) + rl63(scan64_add(r1pp));
    const float spg = rl63(c_pg) + rl63(scan64_add(r1pg));
    const float sg  = rl63(scan64_add(lg));
    const float sgg = rl63(scan64_add(lgg));

    const float invW   = 1.0f / (float)WINDOW;
    const float invWm1 = 1.0f / (float)(WINDOW - 1);
    const float m_g   = sg * invW;
    const float var_g = (sgg - (float)WINDOW * m_g * m_g) * invWm1;

    float cmin = FLT_MAX;
    if (lane < 32) {
        float Sp  = sp  - (c_p  - qp);
        float Spp = spp - (c_pp - qpp);
        float Spg = spg - (c_pg - qpg);
        const int base = lane * 4;
        cmin = ccc_eval(Sp, Spp, Spg, m_g, var_g);                    // r=0
        Sp -= pa.x; Spp -= pa.x*pa.x; Spg -= pa.x*ga.x;               // r=1
        if (base + 1 < NSHIFT) cmin = fminf(cmin, ccc_eval(Sp, Spp, Spg, m_g, var_g));
        Sp -= pa.y; Spp -= pa.y*pa.y; Spg -= pa.y*ga.y;               // r=2
        if (base + 2 < NSHIFT) cmin = fminf(cmin, ccc_eval(Sp, Spp, Spg, m_g, var_g));
        Sp -= pa.z; Spp -= pa.z*pa.z; Spg -= pa.z*ga.z;               // r=3
        if (base + 3 < NSHIFT) cmin = fminf(cmin, ccc_eval(Sp, Spp, Spg, m_g, var_g));
    }
    return wave_min64(cmin);
}

template <bool TWO_STAGE>
__global__ __launch_bounds__(256, 8) void window_ccc_kernel(
    const float4* __restrict__ pred4,
    const float4* __restrict__ gt4,
    float* __restrict__ block_out,
    int num_wins)
{
    __shared__ float s_sum[WPB];
    const int wave   = threadIdx.x >> 6;
    const int lane   = threadIdx.x & 63;
    const int gwaves = gridDim.x * WPB;
    const int gwave  = blockIdx.x * WPB + wave;

    const int  w0 = gwave;
    const int  w1 = gwave + gwaves;
    const int  w2 = gwave + 2 * gwaves;
    const int  w3 = gwave + 3 * gwaves;
    const bool v0 = (w0 < num_wins), v1 = (w1 < num_wins),
               v2 = (w2 < num_wins), v3 = (w3 < num_wins);

    Win A, B;
    load_win(pred4, gt4, v0 ? w0 : 0, lane, A);   // in flight...
    load_win(pred4, gt4, v1 ? w1 : 0, lane, B);   // in flight...

    float ws = 0.f;
    { float cm = compute_win(A, lane); if (v0) ws += cm; }
    load_win(pred4, gt4, v2 ? w2 : 0, lane, A);   // overlap with compute(B)
    { float cm = compute_win(B, lane); if (v1) ws += cm; }
    load_win(pred4, gt4, v3 ? w3 : 0, lane, B);   // overlap with compute(A)
    { float cm = compute_win(A, lane); if (v2) ws += cm; }
    { float cm = compute_win(B, lane); if (v3) ws += cm; }

    if (lane == 0) s_sum[wave] = ws;
    __syncthreads();
    if (threadIdx.x == 0) {
        float s = s_sum[0] + s_sum[1] + s_sum[2] + s_sum[3];
        if (TWO_STAGE) block_out[blockIdx.x] = s;
        else           atomicAdd(block_out, s);
    }
}

__global__ __launch_bounds__(256) void window_ccc_finalize(
    const float* __restrict__ block_sums, int nblocks,
    float* __restrict__ out, int num_wins)
{
    float s = 0.f;
    for (int i = threadIdx.x; i < nblocks; i += 256) s += block_sums[i];
    #pragma unroll
    for (int off = 32; off >= 1; off >>= 1) s += __shfl_xor(s, off);
    __shared__ float ws[4];
    const int wave = threadIdx.x >> 6, lane = threadIdx.x & 63;
    if (lane == 0) ws[wave] = s;
    __syncthreads();
    if (threadIdx.x == 0)
        out[0] = 1.0f - (ws[0] + ws[1] + ws[2] + ws[3]) / (float)num_wins;
}

extern "C" void kernel_launch(void* const* d_in, const int* in_sizes, int n_in,
                              void* d_out, int out_size, void* d_ws, size_t ws_size,
                              hipStream_t stream) {
    const float4* pred4 = (const float4*)d_in[0];
    const float4* gt4   = (const float4*)d_in[1];
    float* out = (float*)d_out;
    float* ws  = (float*)d_ws;

    const int L = in_sizes[0];
    const int num_wins = L / WINDOW;
    const int wins_per_block = WPB * NWPW;                    // 16
    const int nblocks = (num_wins + wins_per_block - 1) / wins_per_block;

    if (ws_size >= (size_t)nblocks * sizeof(float)) {
        window_ccc_kernel<true><<<nblocks, 256, 0, stream>>>(pred4, gt4, ws, num_wins);
        window_ccc_finalize<<<1, 256, 0, stream>>>(ws, nblocks, out, num_wins);
    } else {
        hipMemsetAsync(ws, 0, sizeof(float), stream);
        window_ccc_kernel<false><<<nblocks, 256, 0, stream>>>(pred4, gt4, ws, num_wins);
        window_ccc_finalize<<<1, 256, 0, stream>>>(ws, 1, out, num_wins);
    }
}